// Round 25
// baseline (258.332 us; speedup 1.0000x reference)
//
#include <hip/hip_runtime.h>
#include <stdint.h>

typedef __attribute__((ext_vector_type(8))) short bf16x8;
typedef __attribute__((ext_vector_type(4))) float f32x4;

typedef __attribute__((address_space(3))) uint32_t lds_u32_t;
typedef __attribute__((address_space(1))) const uint32_t glb_u32_t;

static __device__ __forceinline__ ushort f2bf(float f) {
  uint32_t u = __float_as_uint(f);
  uint32_t r = (u + 0x7FFFu + ((u >> 16) & 1u)) >> 16;
  return (ushort)r;
}
static __device__ __forceinline__ float bf2f(ushort u) {
  return __uint_as_float(((uint32_t)u) << 16);
}
// single-instruction f32->bf16 (RNE) via v_cvt_pk_bf16_f32
static __device__ __forceinline__ ushort cvt1(float f) {
  uint32_t u;
  asm("v_cvt_pk_bf16_f32 %0, %1, %1" : "=v"(u) : "v"(f));
  return (ushort)u;
}
// 2^x in one instruction
static __device__ __forceinline__ float exp2f_fast(float x) {
  float r;
  asm("v_exp_f32 %0, %1" : "=v"(r) : "v"(x));
  return r;
}

// ---------------- merged prologue: rmsnorm | rope table | weight casts ----------------
__global__ __launch_bounds__(256) void prologue_kernel(
    const float* __restrict__ x, const float* __restrict__ rmsw,
    ushort* __restrict__ xn, const float* __restrict__ qkv_w,
    ushort* __restrict__ wq, const float* __restrict__ o_w,
    ushort* __restrict__ wo, float* __restrict__ cs, float* __restrict__ sn) {
  const int C = 2048;
  int blk = blockIdx.x;
  int tid = threadIdx.x;
  if (blk < 4096) {
    // ---- RMSNorm row ----
    int lane = tid & 63, wid = tid >> 6;
    const float* xr = x + (size_t)blk * C;
    float4 a = ((const float4*)xr)[tid * 2];
    float4 b = ((const float4*)xr)[tid * 2 + 1];
    float ss = a.x * a.x + a.y * a.y + a.z * a.z + a.w * a.w +
               b.x * b.x + b.y * b.y + b.z * b.z + b.w * b.w;
#pragma unroll
    for (int off = 1; off < 64; off <<= 1) ss += __shfl_xor(ss, off);
    __shared__ float part[4];
    if (lane == 0) part[wid] = ss;
    __syncthreads();
    float tot = part[0] + part[1] + part[2] + part[3];
    float inv = rsqrtf(tot * (1.0f / 2048.0f) + 1e-5f);
    float4 wa = ((const float4*)rmsw)[tid * 2];
    float4 wb = ((const float4*)rmsw)[tid * 2 + 1];
    ushort* dst = xn + (size_t)blk * C + tid * 8;
    ushort4 o0, o1;
    o0.x = f2bf(a.x * inv * wa.x); o0.y = f2bf(a.y * inv * wa.y);
    o0.z = f2bf(a.z * inv * wa.z); o0.w = f2bf(a.w * inv * wa.w);
    o1.x = f2bf(b.x * inv * wb.x); o1.y = f2bf(b.y * inv * wb.y);
    o1.z = f2bf(b.z * inv * wb.z); o1.w = f2bf(b.w * inv * wb.w);
    ((ushort4*)dst)[0] = o0;
    ((ushort4*)dst)[1] = o1;
  } else if (blk < 4096 + 512) {
    // ---- RoPE cos/sin table [2048][64] ----
    int idx = (blk - 4096) * 256 + tid;
    int t = idx >> 6, j = idx & 63;
    float inv_freq = expf(-(2.0f * (float)j / 128.0f) * 9.210340371976184f);
    float ang = (float)t * inv_freq;
    cs[idx] = cosf(ang);
    sn[idx] = sinf(ang);
  } else {
    // ---- weight casts (grid-stride over float4 elems) ----
    const int n1 = 6144 * 2048 / 4, n2 = 2048 * 2048 / 4;
    int stride = 1280 * 256;
    for (int i = (blk - 4608) * 256 + tid; i < n1 + n2; i += stride) {
      const float* src = (i < n1) ? qkv_w : o_w;
      ushort* dst = (i < n1) ? wq : wo;
      int k = (i < n1) ? i : i - n1;
      float4 v = ((const float4*)src)[k];
      ushort4 o;
      o.x = f2bf(v.x); o.y = f2bf(v.y); o.z = f2bf(v.z); o.w = f2bf(v.w);
      ((ushort4*)dst)[k] = o;
    }
  }
}

// ======= merged QKV GEMM: blocks [0,256) = q+k 256x256 path; [256,512) = v 128x256 path
__global__ __launch_bounds__(512, 2) void gemm_qkv_kernel(
    const ushort* __restrict__ A, const ushort* __restrict__ W,
    const float* __restrict__ bias, ushort* __restrict__ qb,
    ushort* __restrict__ kb, ushort* __restrict__ vb,
    const float* __restrict__ cs, const float* __restrict__ sn) {
  const int K = 2048;
  __shared__ __align__(16) char smem[147456];
  const int tid = threadIdx.x;
  const int lane = tid & 63;
  const int wid = tid >> 6;
  const int wc = wid & 3;
  const int ar = lane & 15, g = lane >> 4;

  if (blockIdx.x < 256) {
    // ================= q+k path: 256x256, BK=64, 2-buf, depth-1 =================
    const int wr = wid >> 2;  // 0..1 -> 128-row half
    int blk = blockIdx.x;
    int swzb = (blk & 7) * 32 + (blk >> 3);
    int tm = swzb & 15, tn = swzb >> 4;  // 16 x 16
    int row0 = tm * 256, col0 = tn * 256;

    auto stageA = [&](int slot, int kt) {
#pragma unroll
      for (int i = 0; i < 4; ++i) {
        int e = (i * 512 + tid) * 16;
        int r = e >> 7, b = e & 127;
        int sb = b ^ ((r & 7) << 4);
        __builtin_amdgcn_global_load_lds(
            (glb_u32_t*)(A + (size_t)(row0 + r) * K + kt * 64 + (sb >> 1)),
            (lds_u32_t*)(smem + slot * 32768 + e), 16, 0, 0);
      }
    };
    auto stageB = [&](int slot, int kt) {
#pragma unroll
      for (int i = 0; i < 4; ++i) {
        int e = (i * 512 + tid) * 16;
        int r = e >> 7, b = e & 127;
        int sb = b ^ ((r & 7) << 4);
        __builtin_amdgcn_global_load_lds(
            (glb_u32_t*)(W + (size_t)(col0 + r) * K + kt * 64 + (sb >> 1)),
            (lds_u32_t*)(smem + 65536 + slot * 32768 + e), 16, 0, 0);
      }
    };

    f32x4 acc[8][4];
#pragma unroll
    for (int m = 0; m < 8; ++m)
#pragma unroll
      for (int n = 0; n < 4; ++n) acc[m][n] = (f32x4){0.f, 0.f, 0.f, 0.f};

    stageA(0, 0);
    stageB(0, 0);
    asm volatile("s_waitcnt vmcnt(0)" ::: "memory");
    asm volatile("s_barrier" ::: "memory");

    const int NT = K / 64;  // 32
    for (int kt = 0; kt < NT; ++kt) {
      int cb = kt & 1, nb = cb ^ 1;
      const char* lAp = (const char*)smem + cb * 32768;
      const char* lBp = (const char*)smem + 65536 + cb * 32768;
      const bool pf = (kt + 1 < NT);
      bf16x8 bF[4][2], aF[4][2];
#pragma unroll
      for (int n = 0; n < 4; ++n) {
        int rr = (wc + n * 4) * 16 + ar;  // n-remap: stripes 64 apart
        int sw = (rr & 7) << 4;
#pragma unroll
        for (int ks = 0; ks < 2; ++ks)
          bF[n][ks] = *(const bf16x8*)(lBp + rr * 128 + ((ks * 64 + g * 16) ^ sw));
      }
#pragma unroll
      for (int m = 0; m < 4; ++m) {
        int rr = wr * 128 + m * 16 + ar;
        int sw = (rr & 7) << 4;
#pragma unroll
        for (int ks = 0; ks < 2; ++ks)
          aF[m][ks] = *(const bf16x8*)(lAp + rr * 128 + ((ks * 64 + g * 16) ^ sw));
      }
      if (pf) { stageA(nb, kt + 1); stageB(nb, kt + 1); }
      __builtin_amdgcn_s_setprio(1);
#pragma unroll
      for (int m = 0; m < 4; ++m)
#pragma unroll
        for (int n = 0; n < 4; ++n)
#pragma unroll
          for (int ks = 0; ks < 2; ++ks)
            acc[m][n] = __builtin_amdgcn_mfma_f32_16x16x32_bf16(aF[m][ks], bF[n][ks],
                                                                acc[m][n], 0, 0, 0);
      __builtin_amdgcn_s_setprio(0);
      bf16x8 aG[4][2];
#pragma unroll
      for (int m = 0; m < 4; ++m) {
        int rr = wr * 128 + (4 + m) * 16 + ar;
        int sw = (rr & 7) << 4;
#pragma unroll
        for (int ks = 0; ks < 2; ++ks)
          aG[m][ks] = *(const bf16x8*)(lAp + rr * 128 + ((ks * 64 + g * 16) ^ sw));
      }
      asm volatile("s_waitcnt vmcnt(0)" ::: "memory");
      asm volatile("s_barrier" ::: "memory");  // publish kt+1; protect buf[cb]
      __builtin_amdgcn_s_setprio(1);
#pragma unroll
      for (int m = 0; m < 4; ++m)
#pragma unroll
        for (int n = 0; n < 4; ++n)
#pragma unroll
          for (int ks = 0; ks < 2; ++ks)
            acc[4 + m][n] = __builtin_amdgcn_mfma_f32_16x16x32_bf16(aG[m][ks], bF[n][ks],
                                                                    acc[4 + m][n], 0, 0, 0);
      __builtin_amdgcn_s_setprio(0);
    }

    // ---------------- fused bias+RoPE+scatter epilogue (q or k) ----------------
    int s = col0 >> 11;  // 0 = q, 1 = k
    int dlo = wc * 16 + ar;  // 0..63
    int hbase = (col0 >> 7) & 15;
    float bv[4];
#pragma unroll
    for (int n = 0; n < 4; ++n) bv[n] = bias[col0 + dlo + n * 64];
    ushort* dst = (s == 0) ? qb : kb;
    const float oscale = (s == 0) ? 0.12751551132892735f : 1.0f;  // 1/sqrt(128)*log2e
    const float* csj = cs + dlo;
    const float* snj = sn + dlo;
#pragma unroll
    for (int m = 0; m < 8; ++m) {
#pragma unroll
      for (int r = 0; r < 4; ++r) {
        int mrow = row0 + wr * 128 + m * 16 + g * 4 + r;
        int bb = mrow >> 11, t = mrow & 2047;
        float cc = csj[t * 64], sv = snj[t * 64];
        size_t rowbase = ((size_t)(bb * 16 + hbase) * 2048 + t) * 128;
        float lo = acc[m][0][r] + bv[0], hi = acc[m][1][r] + bv[1];
        dst[rowbase + dlo] = cvt1((lo * cc - hi * sv) * oscale);
        dst[rowbase + dlo + 64] = cvt1((hi * cc + lo * sv) * oscale);
        size_t rowbase1 = rowbase + (size_t)2048 * 128;  // head+1
        lo = acc[m][2][r] + bv[2]; hi = acc[m][3][r] + bv[3];
        dst[rowbase1 + dlo] = cvt1((lo * cc - hi * sv) * oscale);
        dst[rowbase1 + dlo + 64] = cvt1((hi * cc + lo * sv) * oscale);
      }
    }
  } else {
    // ================= v path: 128x256, BK=64, 3-buf, depth-2 =================
    const int wr = wid >> 2;  // 0..1 -> 64-row half
    const ushort* Wv = W + (size_t)4096 * 2048;
    const float* biasv = bias + 4096;
    int blk = (int)blockIdx.x - 256;
    int swzb = (blk & 7) * 32 + (blk >> 3);
    int tm = swzb & 31, tn = swzb >> 5;  // 32 x 8
    int row0 = tm * 128, col0 = tn * 256;

    auto stageA = [&](int slot, int kt) {
#pragma unroll
      for (int i = 0; i < 2; ++i) {
        int e = (i * 512 + tid) * 16;
        int r = e >> 7, b = e & 127;
        int sb = b ^ ((r & 7) << 4);
        __builtin_amdgcn_global_load_lds(
            (glb_u32_t*)(A + (size_t)(row0 + r) * K + kt * 64 + (sb >> 1)),
            (lds_u32_t*)(smem + slot * 16384 + e), 16, 0, 0);
      }
    };
    auto stageB1 = [&](int slot, int kt, int i) {
      int e = (i * 512 + tid) * 16;
      int r = e >> 7, b = e & 127;
      int sb = b ^ ((r & 7) << 4);
      __builtin_amdgcn_global_load_lds(
          (glb_u32_t*)(Wv + (size_t)(col0 + r) * K + kt * 64 + (sb >> 1)),
          (lds_u32_t*)(smem + 49152 + slot * 32768 + e), 16, 0, 0);
    };

    f32x4 acc[4][4];
#pragma unroll
    for (int m = 0; m < 4; ++m)
#pragma unroll
      for (int n = 0; n < 4; ++n) acc[m][n] = (f32x4){0.f, 0.f, 0.f, 0.f};

    stageA(0, 0);
#pragma unroll
    for (int i = 0; i < 4; ++i) stageB1(0, 0, i);
    stageA(1, 1);
#pragma unroll
    for (int i = 0; i < 4; ++i) stageB1(1, 1, i);
    asm volatile("s_waitcnt vmcnt(6)" ::: "memory");
    asm volatile("s_barrier" ::: "memory");

    const int NT = K / 64;  // 32
    int cur = 0;
    for (int kt = 0; kt < NT; ++kt) {
      int s2 = cur + 2; if (s2 >= 3) s2 -= 3;
      const char* lAp = (const char*)smem + cur * 16384;
      const char* lBp = (const char*)smem + 49152 + cur * 32768;
      const bool pf = (kt + 2 < NT);
      bf16x8 bF[4][2], aF[2][2];
#pragma unroll
      for (int n = 0; n < 4; ++n) {
        int rr = (wc + n * 4) * 16 + ar;
        int sw = (rr & 7) << 4;
#pragma unroll
        for (int ks = 0; ks < 2; ++ks)
          bF[n][ks] = *(const bf16x8*)(lBp + rr * 128 + ((ks * 64 + g * 16) ^ sw));
      }
#pragma unroll
      for (int m = 0; m < 2; ++m) {
        int rr = wr * 64 + m * 16 + ar;
        int sw = (rr & 7) << 4;
#pragma unroll
        for (int ks = 0; ks < 2; ++ks)
          aF[m][ks] = *(const bf16x8*)(lAp + rr * 128 + ((ks * 64 + g * 16) ^ sw));
      }
      if (pf) { stageA(s2, kt + 2); stageB1(s2, kt + 2, 0); }
      __builtin_amdgcn_s_setprio(1);
#pragma unroll
      for (int m = 0; m < 2; ++m)
#pragma unroll
        for (int n = 0; n < 4; ++n)
#pragma unroll
          for (int ks = 0; ks < 2; ++ks)
            acc[m][n] = __builtin_amdgcn_mfma_f32_16x16x32_bf16(aF[m][ks], bF[n][ks],
                                                                acc[m][n], 0, 0, 0);
      __builtin_amdgcn_s_setprio(0);
      bf16x8 aG[2][2];
#pragma unroll
      for (int m = 0; m < 2; ++m) {
        int rr = wr * 64 + (2 + m) * 16 + ar;
        int sw = (rr & 7) << 4;
#pragma unroll
        for (int ks = 0; ks < 2; ++ks)
          aG[m][ks] = *(const bf16x8*)(lAp + rr * 128 + ((ks * 64 + g * 16) ^ sw));
      }
      if (pf) { stageB1(s2, kt + 2, 1); stageB1(s2, kt + 2, 2); stageB1(s2, kt + 2, 3); }
      if (kt < NT - 2) {
        asm volatile("s_waitcnt vmcnt(6)" ::: "memory");
      } else if (kt == NT - 2) {
        asm volatile("s_waitcnt vmcnt(0)" ::: "memory");
      }
      asm volatile("s_barrier" ::: "memory");  // publish barrier (sole barrier per K-tile)
      __builtin_amdgcn_s_setprio(1);
#pragma unroll
      for (int m = 0; m < 2; ++m)
#pragma unroll
        for (int n = 0; n < 4; ++n)
#pragma unroll
          for (int ks = 0; ks < 2; ++ks)
            acc[2 + m][n] = __builtin_amdgcn_mfma_f32_16x16x32_bf16(aG[m][ks], bF[n][ks],
                                                                    acc[2 + m][n], 0, 0, 0);
      __builtin_amdgcn_s_setprio(0);
      cur = cur + 1; if (cur >= 3) cur = 0;
    }

    // v epilogue: vb[((b*16+h)*128 + d)*2048 + t]
    int dlo = wc * 16 + ar;
    int hbase = (col0 >> 7) & 15;
    float bv[4];
#pragma unroll
    for (int n = 0; n < 4; ++n) bv[n] = biasv[col0 + dlo + n * 64];
#pragma unroll
    for (int n = 0; n < 4; ++n) {
      int d = dlo + (n & 1) * 64;
      int hh = hbase + (n >> 1);
      float bvn = bv[n];
#pragma unroll
      for (int m = 0; m < 4; ++m) {
        int t0 = row0 + wr * 64 + m * 16 + g * 4;
        int bb = t0 >> 11, tt0 = t0 & 2047;
        ushort4 o;
        o.x = f2bf(acc[m][n][0] + bvn);
        o.y = f2bf(acc[m][n][1] + bvn);
        o.z = f2bf(acc[m][n][2] + bvn);
        o.w = f2bf(acc[m][n][3] + bvn);
        *(ushort4*)&vb[(((size_t)(bb * 16 + hh) * 128) + d) * 2048 + tt0] = o;
      }
    }
  }
}

// ======= 128x256 GEMM (o-proj), BK=64, 8 waves, 3-buf LDS, depth-2, 1 barrier/K-tile ===
__global__ __launch_bounds__(512, 2) void gemm3p_kernel(
    const ushort* __restrict__ A, const ushort* __restrict__ W,
    const float* __restrict__ bias, float* __restrict__ out) {
  const int K = 2048;
  __shared__ ushort lA[3][128 * 64];  // 16 KB each
  __shared__ ushort lB[3][256 * 64];  // 32 KB each (total 144 KB)
  const int tid = threadIdx.x;
  const int lane = tid & 63;
  const int wid = tid >> 6;
  const int wr = wid >> 2;  // 0..1 -> 64-row half
  const int wc = wid & 3;   // 0..3 -> 16-col stripes (remapped)
  const int ar = lane & 15, g = lane >> 4;

  int cpx = gridDim.x >> 3;
  int swzb = ((int)blockIdx.x & 7) * cpx + ((int)blockIdx.x >> 3);
  int tm = swzb & 31, tn = swzb >> 5;  // 32 x 8
  int row0 = tm * 128, col0 = tn * 256;

  auto stageA = [&](int slot, int kt) {
#pragma unroll
    for (int i = 0; i < 2; ++i) {
      int e = (i * 512 + tid) * 16;
      int r = e >> 7, b = e & 127;
      int sb = b ^ ((r & 7) << 4);
      __builtin_amdgcn_global_load_lds(
          (glb_u32_t*)(A + (size_t)(row0 + r) * K + kt * 64 + (sb >> 1)),
          (lds_u32_t*)((char*)lA[slot] + e), 16, 0, 0);
    }
  };
  auto stageB1 = [&](int slot, int kt, int i) {
    int e = (i * 512 + tid) * 16;
    int r = e >> 7, b = e & 127;
    int sb = b ^ ((r & 7) << 4);
    __builtin_amdgcn_global_load_lds(
        (glb_u32_t*)(W + (size_t)(col0 + r) * K + kt * 64 + (sb >> 1)),
        (lds_u32_t*)((char*)lB[slot] + e), 16, 0, 0);
  };

  f32x4 acc[4][4];
#pragma unroll
  for (int m = 0; m < 4; ++m)
#pragma unroll
    for (int n = 0; n < 4; ++n) acc[m][n] = (f32x4){0.f, 0.f, 0.f, 0.f};

  stageA(0, 0);
#pragma unroll
  for (int i = 0; i < 4; ++i) stageB1(0, 0, i);
  stageA(1, 1);
#pragma unroll
  for (int i = 0; i < 4; ++i) stageB1(1, 1, i);
  asm volatile("s_waitcnt vmcnt(6)" ::: "memory");
  asm volatile("s_barrier" ::: "memory");

  const int NT = K / 64;  // 32
  int cur = 0;
  for (int kt = 0; kt < NT; ++kt) {
    int s2 = cur + 2; if (s2 >= 3) s2 -= 3;
    const char* lAp = (const char*)lA[cur];
    const char* lBp = (const char*)lB[cur];
    const bool pf = (kt + 2 < NT);
    bf16x8 bF[4][2], aF[2][2];
#pragma unroll
    for (int n = 0; n < 4; ++n) {
      int rr = (wc + n * 4) * 16 + ar;
      int sw = (rr & 7) << 4;
#pragma unroll
      for (int ks = 0; ks < 2; ++ks)
        bF[n][ks] = *(const bf16x8*)(lBp + rr * 128 + ((ks * 64 + g * 16) ^ sw));
    }
#pragma unroll
    for (int m = 0; m < 2; ++m) {
      int rr = wr * 64 + m * 16 + ar;
      int sw = (rr & 7) << 4;
#pragma unroll
      for (int ks = 0; ks < 2; ++ks)
        aF[m][ks] = *(const bf16x8*)(lAp + rr * 128 + ((ks * 64 + g * 16) ^ sw));
    }
    if (pf) { stageA(s2, kt + 2); stageB1(s2, kt + 2, 0); }
    __builtin_amdgcn_s_setprio(1);
#pragma unroll
    for (int m = 0; m < 2; ++m)
#pragma unroll
      for (int n = 0; n < 4; ++n)
#pragma unroll
        for (int ks = 0; ks < 2; ++ks)
          acc[m][n] = __builtin_amdgcn_mfma_f32_16x16x32_bf16(aF[m][ks], bF[n][ks],
                                                              acc[m][n], 0, 0, 0);
    __builtin_amdgcn_s_setprio(0);
    bf16x8 aG[2][2];
#pragma unroll
    for (int m = 0; m < 2; ++m) {
      int rr = wr * 64 + (2 + m) * 16 + ar;
      int sw = (rr & 7) << 4;
#pragma unroll
      for (int ks = 0; ks < 2; ++ks)
        aG[m][ks] = *(const bf16x8*)(lAp + rr * 128 + ((ks * 64 + g * 16) ^ sw));
    }
    if (pf) { stageB1(s2, kt + 2, 1); stageB1(s2, kt + 2, 2); stageB1(s2, kt + 2, 3); }
    if (kt < NT - 2) {
      asm volatile("s_waitcnt vmcnt(6)" ::: "memory");
    } else if (kt == NT - 2) {
      asm volatile("s_waitcnt vmcnt(0)" ::: "memory");
    }
    asm volatile("s_barrier" ::: "memory");  // publish barrier (sole barrier per K-tile)
    __builtin_amdgcn_s_setprio(1);
#pragma unroll
    for (int m = 0; m < 2; ++m)
#pragma unroll
      for (int n = 0; n < 4; ++n)
#pragma unroll
        for (int ks = 0; ks < 2; ++ks)
          acc[2 + m][n] = __builtin_amdgcn_mfma_f32_16x16x32_bf16(aG[m][ks], bF[n][ks],
                                                                  acc[2 + m][n], 0, 0, 0);
    __builtin_amdgcn_s_setprio(0);
    cur = cur + 1; if (cur >= 3) cur = 0;
  }

#pragma unroll
  for (int n = 0; n < 4; ++n) {
    int col = col0 + wc * 16 + ar + n * 64;
    float bvn = bias[col];
#pragma unroll
    for (int m = 0; m < 4; ++m) {
#pragma unroll
      for (int r = 0; r < 4; ++r) {
        int mrow = row0 + wr * 64 + m * 16 + g * 4 + r;
        out[(size_t)mrow * 2048 + col] = acc[m][n][r] + bvn;
      }
    }
  }
}

// ------- causal flash attention: 4 waves, QBLK=64, KVBLK=32, 36KB LDS -> 4 blk/CU ------
// grid 1024 (32 bh x 32 qh), big-first dispatch. Dbuf K/V retained; stage-early /
// __syncthreads-late skeleton unchanged. kT[2][32x128] 256B rows (key (r&7)<<4);
// vT[2][128x32] 64B rows (key (r&3)<<4); plds[4][16][32] 64B rows (key (qr&3)<<4).
__global__ __launch_bounds__(256, 4) void attn_kernel(const ushort* __restrict__ Q,
                                                      const ushort* __restrict__ K,
                                                      const ushort* __restrict__ Vt,
                                                      ushort* __restrict__ O) {
  __shared__ ushort kT[2][32 * 128];   // 8 KB x2
  __shared__ ushort vT[2][128 * 32];   // 8 KB x2
  __shared__ ushort plds[4][16][32];   // 1 KB/wave (total 36 KB)
  const int tid = threadIdx.x;
  const int lane = tid & 63, wid = tid >> 6;  // wid 0..3
  const int ar = lane & 15, g = lane >> 4;
  int blk = blockIdx.x;
  int xcd = blk & 7, j = blk >> 3;            // j 0..127
  int bh = xcd * 4 + (j & 3);
  int qh = 31 - (j >> 2);                     // big blocks dispatch first
  int b = bh >> 4, h = bh & 15;
  const ushort* Qb = Q + (size_t)bh * (2048 * 128);
  const ushort* Kb = K + (size_t)bh * (2048 * 128);
  const ushort* Vtb = Vt + (size_t)bh * (128 * 2048);
  int qrow0 = qh * 64 + wid * 16;

  auto stage = [&](int buf, int tt) {
    int kv0 = tt * 32;
#pragma unroll
    for (int i = 0; i < 2; ++i) {
      int e = (i * 256 + tid) * 16;  // byte offset, covers 8KB each
      {
        int r = e >> 8, bs = (e & 255) ^ ((r & 7) << 4);
        __builtin_amdgcn_global_load_lds(
            (glb_u32_t*)(Kb + (size_t)(kv0 + r) * 128 + (bs >> 1)),
            (lds_u32_t*)((char*)kT[buf] + e), 16, 0, 0);
      }
      {
        int r = e >> 6, bs = (e & 63) ^ ((r & 3) << 4);
        __builtin_amdgcn_global_load_lds(
            (glb_u32_t*)(Vtb + (size_t)r * 2048 + kv0 + (bs >> 1)),
            (lds_u32_t*)((char*)vT[buf] + e), 16, 0, 0);
      }
    }
  };

  bf16x8 qf[4];
#pragma unroll
  for (int kk = 0; kk < 4; ++kk)
    qf[kk] = *(const bf16x8*)&Qb[(size_t)(qrow0 + ar) * 128 + kk * 32 + g * 8];
  bf16x8 vone;
#pragma unroll
  for (int jv = 0; jv < 8; ++jv) vone[jv] = (short)0x3F80;  // bf16 1.0
  float m_r[4] = {-1e30f, -1e30f, -1e30f, -1e30f};
  f32x4 lacc = (f32x4){0.f, 0.f, 0.f, 0.f};
  f32x4 accO[8];
#pragma unroll
  for (int n = 0; n < 8; ++n) accO[n] = (f32x4){0.f, 0.f, 0.f, 0.f};

  int nt = 2 * qh + 2;
  stage(0, 0);
  __syncthreads();  // publish tile 0
  for (int tt = 0; tt < nt; ++tt) {
    int cb = tt & 1;
    if (tt + 1 < nt) stage(cb ^ 1, tt + 1);  // issue early; covered by compute
    int kv0 = tt * 32;
    const ushort* kTb = kT[cb];
    const ushort* vTb = vT[cb];
    // ---- QK^T (2 n-frags over 32 kv) ----
    f32x4 s4[2];
    __builtin_amdgcn_s_setprio(1);
#pragma unroll
    for (int n = 0; n < 2; ++n) {
      s4[n] = (f32x4){0.f, 0.f, 0.f, 0.f};
      int r = n * 16 + ar;
      int swz = (r & 7) << 4;
#pragma unroll
      for (int kk = 0; kk < 4; ++kk) {
        int byte = (kk * 64 + g * 16) ^ swz;
        bf16x8 kf = *(const bf16x8*)&kTb[((r << 8) + byte) >> 1];
        s4[n] = __builtin_amdgcn_mfma_f32_16x16x32_bf16(qf[kk], kf, s4[n], 0, 0, 0);
      }
    }
    __builtin_amdgcn_s_setprio(0);
    // ---- softmax (log2 domain): max-reduce, defer-max rescale, exp2, pack ----
    const bool masked = (kv0 + 31 > qrow0);  // diagonal/above tiles
    float pv[4][2];
    float pmax[4];
#pragma unroll
    for (int r = 0; r < 4; ++r) {
      float v0 = s4[0][r], v1 = s4[1][r];
      if (masked) {
        int row = qrow0 + g * 4 + r;
        v0 = (kv0 + ar > row) ? -1e30f : v0;
        v1 = (kv0 + 16 + ar > row) ? -1e30f : v1;
      }
      float mx = fmaxf(v0, v1);
#pragma unroll
      for (int off = 1; off < 16; off <<= 1) mx = fmaxf(mx, __shfl_xor(mx, off));
      pmax[r] = mx;
      pv[r][0] = v0; pv[r][1] = v1;
    }
    int nore = (pmax[0] - m_r[0] <= 8.f) && (pmax[1] - m_r[1] <= 8.f) &&
               (pmax[2] - m_r[2] <= 8.f) && (pmax[3] - m_r[3] <= 8.f);
    if (!__all(nore)) {  // wave-uniform rescale (first tile always lands here)
#pragma unroll
      for (int r = 0; r < 4; ++r) {
        float mn = fmaxf(m_r[r], pmax[r]);
        float c = exp2f_fast(m_r[r] - mn);
        m_r[r] = mn;
        lacc[r] *= c;
#pragma unroll
        for (int n = 0; n < 8; ++n) accO[n][r] *= c;
      }
    }
#pragma unroll
    for (int r = 0; r < 4; ++r) {
      int qr = g * 4 + r;
      int key = (qr & 3) << 4;
      char* prow = (char*)&plds[wid][0][0] + qr * 64;
#pragma unroll
      for (int n = 0; n < 2; ++n) {
        float p = exp2f_fast(pv[r][n] - m_r[r]);
        *(ushort*)(prow + ((32 * n + 2 * ar) ^ key)) = cvt1(p);
      }
    }
    asm volatile("s_waitcnt lgkmcnt(0)" ::: "memory");
    // ---- PV + row-sum-by-ones (single K=32 MFMA per n-frag) ----
    int keyr = (ar & 3) << 4;
    const char* pbase = (const char*)&plds[wid][0][0] + ar * 64;
    bf16x8 pf0 = *(const bf16x8*)(pbase + ((g * 16) ^ keyr));
    __builtin_amdgcn_s_setprio(1);
#pragma unroll
    for (int n = 0; n < 8; ++n) {
      int r = n * 16 + ar;
      int swz = (r & 3) << 4;
      bf16x8 vf0 = *(const bf16x8*)&vTb[((r << 6) + ((g * 16) ^ swz)) >> 1];
      accO[n] = __builtin_amdgcn_mfma_f32_16x16x32_bf16(pf0, vf0, accO[n], 0, 0, 0);
    }
    lacc = __builtin_amdgcn_mfma_f32_16x16x32_bf16(pf0, vone, lacc, 0, 0, 0);
    __builtin_amdgcn_s_setprio(0);
    // full drain (vmcnt+lgkm) + barrier: publishes next tile, protects buffers
    __syncthreads();
  }
  // write O to [B,T,H*D] (bf16) for the O-proj GEMM
#pragma unroll
  for (int r = 0; r < 4; ++r) {
    int trow = qrow0 + g * 4 + r;
    float invl = 1.0f / lacc[r];
    ushort* orow = O + ((size_t)b * 2048 + trow) * 2048 + h * 128;
#pragma unroll
    for (int n = 0; n < 8; ++n) orow[n * 16 + ar] = cvt1(accO[n][r] * invl);
  }
}

extern "C" void kernel_launch(void* const* d_in, const int* in_sizes, int n_in,
                              void* d_out, int out_size, void* d_ws, size_t ws_size,
                              hipStream_t stream) {
  const float* x = (const float*)d_in[0];
  const float* rmsw = (const float*)d_in[1];
  const float* qkv_w = (const float*)d_in[2];
  const float* qkv_b = (const float*)d_in[3];
  const float* o_w = (const float*)d_in[4];
  const float* o_b = (const float*)d_in[5];
  float* out = (float*)d_out;

  char* ws = (char*)d_ws;
  size_t off = 0;
  auto alloc = [&](size_t bytes) {
    void* p = ws + off;
    off += (bytes + 255) & ~(size_t)255;
    return p;
  };
  ushort* xn = (ushort*)alloc((size_t)4096 * 2048 * 2);  // later reused as attn_out
  ushort* wq = (ushort*)alloc((size_t)6144 * 2048 * 2);
  ushort* wo = (ushort*)alloc((size_t)2048 * 2048 * 2);
  ushort* qb = (ushort*)alloc((size_t)32 * 2048 * 128 * 2);
  ushort* kb = (ushort*)alloc((size_t)32 * 2048 * 128 * 2);
  ushort* vb = (ushort*)alloc((size_t)32 * 2048 * 128 * 2);  // [B,H,D,T]
  float* cs = (float*)alloc((size_t)2048 * 64 * 4);
  float* sn = (float*)alloc((size_t)2048 * 64 * 4);

  // merged prologue: rmsnorm (4096 blocks) + rope table (512) + weight casts (1280)
  prologue_kernel<<<5888, 256, 0, stream>>>(x, rmsw, xn, qkv_w, wq, o_w, wo, cs, sn);
  // merged QKV: blocks [0,256) = q+k 256x256 (1 round); [256,512) = v 128x256
  gemm_qkv_kernel<<<512, 512, 0, stream>>>(xn, wq, qkv_b, qb, kb, vb, cs, sn);
  attn_kernel<<<1024, 256, 0, stream>>>(qb, kb, vb, xn /* attn_out */);
  // O-proj: M=4096 (32) x N=2048 (8) -> 256 blocks = 1 exact wave
  gemm3p_kernel<<<256, 512, 0, stream>>>(xn, wo, o_b, out);
}

// Round 26
// 226.245 us; speedup vs baseline: 1.1418x; 1.1418x over previous
//
#include <hip/hip_runtime.h>
#include <stdint.h>

typedef __attribute__((ext_vector_type(8))) short bf16x8;
typedef __attribute__((ext_vector_type(4))) float f32x4;

typedef __attribute__((address_space(3))) uint32_t lds_u32_t;
typedef __attribute__((address_space(1))) const uint32_t glb_u32_t;

static __device__ __forceinline__ ushort f2bf(float f) {
  uint32_t u = __float_as_uint(f);
  uint32_t r = (u + 0x7FFFu + ((u >> 16) & 1u)) >> 16;
  return (ushort)r;
}
static __device__ __forceinline__ float bf2f(ushort u) {
  return __uint_as_float(((uint32_t)u) << 16);
}
// single-instruction f32->bf16 (RNE) via v_cvt_pk_bf16_f32
static __device__ __forceinline__ ushort cvt1(float f) {
  uint32_t u;
  asm("v_cvt_pk_bf16_f32 %0, %1, %1" : "=v"(u) : "v"(f));
  return (ushort)u;
}
// 2^x in one instruction
static __device__ __forceinline__ float exp2f_fast(float x) {
  float r;
  asm("v_exp_f32 %0, %1" : "=v"(r) : "v"(x));
  return r;
}

// ---------------- merged prologue: rmsnorm | rope table | weight casts ----------------
__global__ __launch_bounds__(256) void prologue_kernel(
    const float* __restrict__ x, const float* __restrict__ rmsw,
    ushort* __restrict__ xn, const float* __restrict__ qkv_w,
    ushort* __restrict__ wq, const float* __restrict__ o_w,
    ushort* __restrict__ wo, float* __restrict__ cs, float* __restrict__ sn) {
  const int C = 2048;
  int blk = blockIdx.x;
  int tid = threadIdx.x;
  if (blk < 4096) {
    // ---- RMSNorm row ----
    int lane = tid & 63, wid = tid >> 6;
    const float* xr = x + (size_t)blk * C;
    float4 a = ((const float4*)xr)[tid * 2];
    float4 b = ((const float4*)xr)[tid * 2 + 1];
    float ss = a.x * a.x + a.y * a.y + a.z * a.z + a.w * a.w +
               b.x * b.x + b.y * b.y + b.z * b.z + b.w * b.w;
#pragma unroll
    for (int off = 1; off < 64; off <<= 1) ss += __shfl_xor(ss, off);
    __shared__ float part[4];
    if (lane == 0) part[wid] = ss;
    __syncthreads();
    float tot = part[0] + part[1] + part[2] + part[3];
    float inv = rsqrtf(tot * (1.0f / 2048.0f) + 1e-5f);
    float4 wa = ((const float4*)rmsw)[tid * 2];
    float4 wb = ((const float4*)rmsw)[tid * 2 + 1];
    ushort* dst = xn + (size_t)blk * C + tid * 8;
    ushort4 o0, o1;
    o0.x = f2bf(a.x * inv * wa.x); o0.y = f2bf(a.y * inv * wa.y);
    o0.z = f2bf(a.z * inv * wa.z); o0.w = f2bf(a.w * inv * wa.w);
    o1.x = f2bf(b.x * inv * wb.x); o1.y = f2bf(b.y * inv * wb.y);
    o1.z = f2bf(b.z * inv * wb.z); o1.w = f2bf(b.w * inv * wb.w);
    ((ushort4*)dst)[0] = o0;
    ((ushort4*)dst)[1] = o1;
  } else if (blk < 4096 + 512) {
    // ---- RoPE cos/sin table [2048][64] ----
    int idx = (blk - 4096) * 256 + tid;
    int t = idx >> 6, j = idx & 63;
    float inv_freq = expf(-(2.0f * (float)j / 128.0f) * 9.210340371976184f);
    float ang = (float)t * inv_freq;
    cs[idx] = cosf(ang);
    sn[idx] = sinf(ang);
  } else {
    // ---- weight casts (grid-stride over float4 elems) ----
    const int n1 = 6144 * 2048 / 4, n2 = 2048 * 2048 / 4;
    int stride = 1280 * 256;
    for (int i = (blk - 4608) * 256 + tid; i < n1 + n2; i += stride) {
      const float* src = (i < n1) ? qkv_w : o_w;
      ushort* dst = (i < n1) ? wq : wo;
      int k = (i < n1) ? i : i - n1;
      float4 v = ((const float4*)src)[k];
      ushort4 o;
      o.x = f2bf(v.x); o.y = f2bf(v.y); o.z = f2bf(v.z); o.w = f2bf(v.w);
      ((ushort4*)dst)[k] = o;
    }
  }
}

// ======= merged QKV GEMM: blocks [0,256) = q+k 256x256 path; [256,512) = v 128x256 path
__global__ __launch_bounds__(512, 2) void gemm_qkv_kernel(
    const ushort* __restrict__ A, const ushort* __restrict__ W,
    const float* __restrict__ bias, ushort* __restrict__ qb,
    ushort* __restrict__ kb, ushort* __restrict__ vb,
    const float* __restrict__ cs, const float* __restrict__ sn) {
  const int K = 2048;
  __shared__ __align__(16) char smem[147456];
  const int tid = threadIdx.x;
  const int lane = tid & 63;
  const int wid = tid >> 6;
  const int wc = wid & 3;
  const int ar = lane & 15, g = lane >> 4;

  if (blockIdx.x < 256) {
    // ================= q+k path: 256x256, BK=64, 2-buf, depth-1 =================
    const int wr = wid >> 2;  // 0..1 -> 128-row half
    int blk = blockIdx.x;
    int swzb = (blk & 7) * 32 + (blk >> 3);
    int tm = swzb & 15, tn = swzb >> 4;  // 16 x 16
    int row0 = tm * 256, col0 = tn * 256;

    auto stageA = [&](int slot, int kt) {
#pragma unroll
      for (int i = 0; i < 4; ++i) {
        int e = (i * 512 + tid) * 16;
        int r = e >> 7, b = e & 127;
        int sb = b ^ ((r & 7) << 4);
        __builtin_amdgcn_global_load_lds(
            (glb_u32_t*)(A + (size_t)(row0 + r) * K + kt * 64 + (sb >> 1)),
            (lds_u32_t*)(smem + slot * 32768 + e), 16, 0, 0);
      }
    };
    auto stageB = [&](int slot, int kt) {
#pragma unroll
      for (int i = 0; i < 4; ++i) {
        int e = (i * 512 + tid) * 16;
        int r = e >> 7, b = e & 127;
        int sb = b ^ ((r & 7) << 4);
        __builtin_amdgcn_global_load_lds(
            (glb_u32_t*)(W + (size_t)(col0 + r) * K + kt * 64 + (sb >> 1)),
            (lds_u32_t*)(smem + 65536 + slot * 32768 + e), 16, 0, 0);
      }
    };

    f32x4 acc[8][4];
#pragma unroll
    for (int m = 0; m < 8; ++m)
#pragma unroll
      for (int n = 0; n < 4; ++n) acc[m][n] = (f32x4){0.f, 0.f, 0.f, 0.f};

    stageA(0, 0);
    stageB(0, 0);
    asm volatile("s_waitcnt vmcnt(0)" ::: "memory");
    asm volatile("s_barrier" ::: "memory");

    const int NT = K / 64;  // 32
    for (int kt = 0; kt < NT; ++kt) {
      int cb = kt & 1, nb = cb ^ 1;
      const char* lAp = (const char*)smem + cb * 32768;
      const char* lBp = (const char*)smem + 65536 + cb * 32768;
      const bool pf = (kt + 1 < NT);
      bf16x8 bF[4][2], aF[4][2];
#pragma unroll
      for (int n = 0; n < 4; ++n) {
        int rr = (wc + n * 4) * 16 + ar;  // n-remap: stripes 64 apart
        int sw = (rr & 7) << 4;
#pragma unroll
        for (int ks = 0; ks < 2; ++ks)
          bF[n][ks] = *(const bf16x8*)(lBp + rr * 128 + ((ks * 64 + g * 16) ^ sw));
      }
#pragma unroll
      for (int m = 0; m < 4; ++m) {
        int rr = wr * 128 + m * 16 + ar;
        int sw = (rr & 7) << 4;
#pragma unroll
        for (int ks = 0; ks < 2; ++ks)
          aF[m][ks] = *(const bf16x8*)(lAp + rr * 128 + ((ks * 64 + g * 16) ^ sw));
      }
      if (pf) { stageA(nb, kt + 1); stageB(nb, kt + 1); }
      __builtin_amdgcn_s_setprio(1);
#pragma unroll
      for (int m = 0; m < 4; ++m)
#pragma unroll
        for (int n = 0; n < 4; ++n)
#pragma unroll
          for (int ks = 0; ks < 2; ++ks)
            acc[m][n] = __builtin_amdgcn_mfma_f32_16x16x32_bf16(aF[m][ks], bF[n][ks],
                                                                acc[m][n], 0, 0, 0);
      __builtin_amdgcn_s_setprio(0);
      bf16x8 aG[4][2];
#pragma unroll
      for (int m = 0; m < 4; ++m) {
        int rr = wr * 128 + (4 + m) * 16 + ar;
        int sw = (rr & 7) << 4;
#pragma unroll
        for (int ks = 0; ks < 2; ++ks)
          aG[m][ks] = *(const bf16x8*)(lAp + rr * 128 + ((ks * 64 + g * 16) ^ sw));
      }
      asm volatile("s_waitcnt vmcnt(0)" ::: "memory");
      asm volatile("s_barrier" ::: "memory");  // publish kt+1; protect buf[cb]
      __builtin_amdgcn_s_setprio(1);
#pragma unroll
      for (int m = 0; m < 4; ++m)
#pragma unroll
        for (int n = 0; n < 4; ++n)
#pragma unroll
          for (int ks = 0; ks < 2; ++ks)
            acc[4 + m][n] = __builtin_amdgcn_mfma_f32_16x16x32_bf16(aG[m][ks], bF[n][ks],
                                                                    acc[4 + m][n], 0, 0, 0);
      __builtin_amdgcn_s_setprio(0);
    }

    // ---------------- fused bias+RoPE+scatter epilogue (q or k) ----------------
    int s = col0 >> 11;  // 0 = q, 1 = k
    int dlo = wc * 16 + ar;  // 0..63
    int hbase = (col0 >> 7) & 15;
    float bv[4];
#pragma unroll
    for (int n = 0; n < 4; ++n) bv[n] = bias[col0 + dlo + n * 64];
    ushort* dst = (s == 0) ? qb : kb;
    const float oscale = (s == 0) ? 0.12751551132892735f : 1.0f;  // 1/sqrt(128)*log2e
    const float* csj = cs + dlo;
    const float* snj = sn + dlo;
#pragma unroll
    for (int m = 0; m < 8; ++m) {
#pragma unroll
      for (int r = 0; r < 4; ++r) {
        int mrow = row0 + wr * 128 + m * 16 + g * 4 + r;
        int bb = mrow >> 11, t = mrow & 2047;
        float cc = csj[t * 64], sv = snj[t * 64];
        size_t rowbase = ((size_t)(bb * 16 + hbase) * 2048 + t) * 128;
        float lo = acc[m][0][r] + bv[0], hi = acc[m][1][r] + bv[1];
        dst[rowbase + dlo] = cvt1((lo * cc - hi * sv) * oscale);
        dst[rowbase + dlo + 64] = cvt1((hi * cc + lo * sv) * oscale);
        size_t rowbase1 = rowbase + (size_t)2048 * 128;  // head+1
        lo = acc[m][2][r] + bv[2]; hi = acc[m][3][r] + bv[3];
        dst[rowbase1 + dlo] = cvt1((lo * cc - hi * sv) * oscale);
        dst[rowbase1 + dlo + 64] = cvt1((hi * cc + lo * sv) * oscale);
      }
    }
  } else {
    // ================= v path: 128x256, BK=64, 3-buf, depth-2 =================
    const int wr = wid >> 2;  // 0..1 -> 64-row half
    const ushort* Wv = W + (size_t)4096 * 2048;
    const float* biasv = bias + 4096;
    int blk = (int)blockIdx.x - 256;
    int swzb = (blk & 7) * 32 + (blk >> 3);
    int tm = swzb & 31, tn = swzb >> 5;  // 32 x 8
    int row0 = tm * 128, col0 = tn * 256;

    auto stageA = [&](int slot, int kt) {
#pragma unroll
      for (int i = 0; i < 2; ++i) {
        int e = (i * 512 + tid) * 16;
        int r = e >> 7, b = e & 127;
        int sb = b ^ ((r & 7) << 4);
        __builtin_amdgcn_global_load_lds(
            (glb_u32_t*)(A + (size_t)(row0 + r) * K + kt * 64 + (sb >> 1)),
            (lds_u32_t*)(smem + slot * 16384 + e), 16, 0, 0);
      }
    };
    auto stageB1 = [&](int slot, int kt, int i) {
      int e = (i * 512 + tid) * 16;
      int r = e >> 7, b = e & 127;
      int sb = b ^ ((r & 7) << 4);
      __builtin_amdgcn_global_load_lds(
          (glb_u32_t*)(Wv + (size_t)(col0 + r) * K + kt * 64 + (sb >> 1)),
          (lds_u32_t*)(smem + 49152 + slot * 32768 + e), 16, 0, 0);
    };

    f32x4 acc[4][4];
#pragma unroll
    for (int m = 0; m < 4; ++m)
#pragma unroll
      for (int n = 0; n < 4; ++n) acc[m][n] = (f32x4){0.f, 0.f, 0.f, 0.f};

    stageA(0, 0);
#pragma unroll
    for (int i = 0; i < 4; ++i) stageB1(0, 0, i);
    stageA(1, 1);
#pragma unroll
    for (int i = 0; i < 4; ++i) stageB1(1, 1, i);
    asm volatile("s_waitcnt vmcnt(6)" ::: "memory");
    asm volatile("s_barrier" ::: "memory");

    const int NT = K / 64;  // 32
    int cur = 0;
    for (int kt = 0; kt < NT; ++kt) {
      int s2 = cur + 2; if (s2 >= 3) s2 -= 3;
      const char* lAp = (const char*)smem + cur * 16384;
      const char* lBp = (const char*)smem + 49152 + cur * 32768;
      const bool pf = (kt + 2 < NT);
      bf16x8 bF[4][2], aF[2][2];
#pragma unroll
      for (int n = 0; n < 4; ++n) {
        int rr = (wc + n * 4) * 16 + ar;
        int sw = (rr & 7) << 4;
#pragma unroll
        for (int ks = 0; ks < 2; ++ks)
          bF[n][ks] = *(const bf16x8*)(lBp + rr * 128 + ((ks * 64 + g * 16) ^ sw));
      }
#pragma unroll
      for (int m = 0; m < 2; ++m) {
        int rr = wr * 64 + m * 16 + ar;
        int sw = (rr & 7) << 4;
#pragma unroll
        for (int ks = 0; ks < 2; ++ks)
          aF[m][ks] = *(const bf16x8*)(lAp + rr * 128 + ((ks * 64 + g * 16) ^ sw));
      }
      if (pf) { stageA(s2, kt + 2); stageB1(s2, kt + 2, 0); }
      __builtin_amdgcn_s_setprio(1);
#pragma unroll
      for (int m = 0; m < 2; ++m)
#pragma unroll
        for (int n = 0; n < 4; ++n)
#pragma unroll
          for (int ks = 0; ks < 2; ++ks)
            acc[m][n] = __builtin_amdgcn_mfma_f32_16x16x32_bf16(aF[m][ks], bF[n][ks],
                                                                acc[m][n], 0, 0, 0);
      __builtin_amdgcn_s_setprio(0);
      bf16x8 aG[2][2];
#pragma unroll
      for (int m = 0; m < 2; ++m) {
        int rr = wr * 64 + (2 + m) * 16 + ar;
        int sw = (rr & 7) << 4;
#pragma unroll
        for (int ks = 0; ks < 2; ++ks)
          aG[m][ks] = *(const bf16x8*)(lAp + rr * 128 + ((ks * 64 + g * 16) ^ sw));
      }
      if (pf) { stageB1(s2, kt + 2, 1); stageB1(s2, kt + 2, 2); stageB1(s2, kt + 2, 3); }
      if (kt < NT - 2) {
        asm volatile("s_waitcnt vmcnt(6)" ::: "memory");
      } else if (kt == NT - 2) {
        asm volatile("s_waitcnt vmcnt(0)" ::: "memory");
      }
      asm volatile("s_barrier" ::: "memory");  // publish barrier (sole barrier per K-tile)
      __builtin_amdgcn_s_setprio(1);
#pragma unroll
      for (int m = 0; m < 2; ++m)
#pragma unroll
        for (int n = 0; n < 4; ++n)
#pragma unroll
          for (int ks = 0; ks < 2; ++ks)
            acc[2 + m][n] = __builtin_amdgcn_mfma_f32_16x16x32_bf16(aG[m][ks], bF[n][ks],
                                                                    acc[2 + m][n], 0, 0, 0);
      __builtin_amdgcn_s_setprio(0);
      cur = cur + 1; if (cur >= 3) cur = 0;
    }

    // v epilogue: vb[((b*16+h)*128 + d)*2048 + t]
    int dlo = wc * 16 + ar;
    int hbase = (col0 >> 7) & 15;
    float bv[4];
#pragma unroll
    for (int n = 0; n < 4; ++n) bv[n] = biasv[col0 + dlo + n * 64];
#pragma unroll
    for (int n = 0; n < 4; ++n) {
      int d = dlo + (n & 1) * 64;
      int hh = hbase + (n >> 1);
      float bvn = bv[n];
#pragma unroll
      for (int m = 0; m < 4; ++m) {
        int t0 = row0 + wr * 64 + m * 16 + g * 4;
        int bb = t0 >> 11, tt0 = t0 & 2047;
        ushort4 o;
        o.x = f2bf(acc[m][n][0] + bvn);
        o.y = f2bf(acc[m][n][1] + bvn);
        o.z = f2bf(acc[m][n][2] + bvn);
        o.w = f2bf(acc[m][n][3] + bvn);
        *(ushort4*)&vb[(((size_t)(bb * 16 + hh) * 128) + d) * 2048 + tt0] = o;
      }
    }
  }
}

// ======= 128x256 GEMM (o-proj), BK=64, 8 waves, 3-buf LDS, depth-2, 1 barrier/K-tile ===
__global__ __launch_bounds__(512, 2) void gemm3p_kernel(
    const ushort* __restrict__ A, const ushort* __restrict__ W,
    const float* __restrict__ bias, float* __restrict__ out) {
  const int K = 2048;
  __shared__ ushort lA[3][128 * 64];  // 16 KB each
  __shared__ ushort lB[3][256 * 64];  // 32 KB each (total 144 KB)
  const int tid = threadIdx.x;
  const int lane = tid & 63;
  const int wid = tid >> 6;
  const int wr = wid >> 2;  // 0..1 -> 64-row half
  const int wc = wid & 3;   // 0..3 -> 16-col stripes (remapped)
  const int ar = lane & 15, g = lane >> 4;

  int cpx = gridDim.x >> 3;
  int swzb = ((int)blockIdx.x & 7) * cpx + ((int)blockIdx.x >> 3);
  int tm = swzb & 31, tn = swzb >> 5;  // 32 x 8
  int row0 = tm * 128, col0 = tn * 256;

  auto stageA = [&](int slot, int kt) {
#pragma unroll
    for (int i = 0; i < 2; ++i) {
      int e = (i * 512 + tid) * 16;
      int r = e >> 7, b = e & 127;
      int sb = b ^ ((r & 7) << 4);
      __builtin_amdgcn_global_load_lds(
          (glb_u32_t*)(A + (size_t)(row0 + r) * K + kt * 64 + (sb >> 1)),
          (lds_u32_t*)((char*)lA[slot] + e), 16, 0, 0);
    }
  };
  auto stageB1 = [&](int slot, int kt, int i) {
    int e = (i * 512 + tid) * 16;
    int r = e >> 7, b = e & 127;
    int sb = b ^ ((r & 7) << 4);
    __builtin_amdgcn_global_load_lds(
        (glb_u32_t*)(W + (size_t)(col0 + r) * K + kt * 64 + (sb >> 1)),
        (lds_u32_t*)((char*)lB[slot] + e), 16, 0, 0);
  };

  f32x4 acc[4][4];
#pragma unroll
  for (int m = 0; m < 4; ++m)
#pragma unroll
    for (int n = 0; n < 4; ++n) acc[m][n] = (f32x4){0.f, 0.f, 0.f, 0.f};

  stageA(0, 0);
#pragma unroll
  for (int i = 0; i < 4; ++i) stageB1(0, 0, i);
  stageA(1, 1);
#pragma unroll
  for (int i = 0; i < 4; ++i) stageB1(1, 1, i);
  asm volatile("s_waitcnt vmcnt(6)" ::: "memory");
  asm volatile("s_barrier" ::: "memory");

  const int NT = K / 64;  // 32
  int cur = 0;
  for (int kt = 0; kt < NT; ++kt) {
    int s2 = cur + 2; if (s2 >= 3) s2 -= 3;
    const char* lAp = (const char*)lA[cur];
    const char* lBp = (const char*)lB[cur];
    const bool pf = (kt + 2 < NT);
    bf16x8 bF[4][2], aF[2][2];
#pragma unroll
    for (int n = 0; n < 4; ++n) {
      int rr = (wc + n * 4) * 16 + ar;
      int sw = (rr & 7) << 4;
#pragma unroll
      for (int ks = 0; ks < 2; ++ks)
        bF[n][ks] = *(const bf16x8*)(lBp + rr * 128 + ((ks * 64 + g * 16) ^ sw));
    }
#pragma unroll
    for (int m = 0; m < 2; ++m) {
      int rr = wr * 64 + m * 16 + ar;
      int sw = (rr & 7) << 4;
#pragma unroll
      for (int ks = 0; ks < 2; ++ks)
        aF[m][ks] = *(const bf16x8*)(lAp + rr * 128 + ((ks * 64 + g * 16) ^ sw));
    }
    if (pf) { stageA(s2, kt + 2); stageB1(s2, kt + 2, 0); }
    __builtin_amdgcn_s_setprio(1);
#pragma unroll
    for (int m = 0; m < 2; ++m)
#pragma unroll
      for (int n = 0; n < 4; ++n)
#pragma unroll
        for (int ks = 0; ks < 2; ++ks)
          acc[m][n] = __builtin_amdgcn_mfma_f32_16x16x32_bf16(aF[m][ks], bF[n][ks],
                                                              acc[m][n], 0, 0, 0);
    __builtin_amdgcn_s_setprio(0);
    bf16x8 aG[2][2];
#pragma unroll
    for (int m = 0; m < 2; ++m) {
      int rr = wr * 64 + (2 + m) * 16 + ar;
      int sw = (rr & 7) << 4;
#pragma unroll
      for (int ks = 0; ks < 2; ++ks)
        aG[m][ks] = *(const bf16x8*)(lAp + rr * 128 + ((ks * 64 + g * 16) ^ sw));
    }
    if (pf) { stageB1(s2, kt + 2, 1); stageB1(s2, kt + 2, 2); stageB1(s2, kt + 2, 3); }
    if (kt < NT - 2) {
      asm volatile("s_waitcnt vmcnt(6)" ::: "memory");
    } else if (kt == NT - 2) {
      asm volatile("s_waitcnt vmcnt(0)" ::: "memory");
    }
    asm volatile("s_barrier" ::: "memory");  // publish barrier (sole barrier per K-tile)
    __builtin_amdgcn_s_setprio(1);
#pragma unroll
    for (int m = 0; m < 2; ++m)
#pragma unroll
      for (int n = 0; n < 4; ++n)
#pragma unroll
        for (int ks = 0; ks < 2; ++ks)
          acc[2 + m][n] = __builtin_amdgcn_mfma_f32_16x16x32_bf16(aG[m][ks], bF[n][ks],
                                                                  acc[2 + m][n], 0, 0, 0);
    __builtin_amdgcn_s_setprio(0);
    cur = cur + 1; if (cur >= 3) cur = 0;
  }

#pragma unroll
  for (int n = 0; n < 4; ++n) {
    int col = col0 + wc * 16 + ar + n * 64;
    float bvn = bias[col];
#pragma unroll
    for (int m = 0; m < 4; ++m) {
#pragma unroll
      for (int r = 0; r < 4; ++r) {
        int mrow = row0 + wr * 64 + m * 16 + g * 4 + r;
        out[(size_t)mrow * 2048 + col] = acc[m][n][r] + bvn;
      }
    }
  }
}

// ------- causal flash attention: 4 waves, QBLK=64, 1024 oversubscribed blocks ---------
// grid 1024 (32 bh x 32 qh), big-first dispatch -> scheduler backfills as short blocks
// finish. Dbuf K/V + stage-early/sync-late (verified r21/r23 config, 81us).
__global__ __launch_bounds__(256, 2) void attn_kernel(const ushort* __restrict__ Q,
                                                      const ushort* __restrict__ K,
                                                      const ushort* __restrict__ Vt,
                                                      ushort* __restrict__ O) {
  __shared__ ushort kT[2][64 * 128];   // 16 KB x2, rows 256B, XOR-swizzled
  __shared__ ushort vT[2][128 * 64];   // 16 KB x2, rows 128B, XOR-swizzled
  __shared__ ushort plds[4][16][64];   // 2 KB/wave (total 72 KB)
  const int tid = threadIdx.x;
  const int lane = tid & 63, wid = tid >> 6;  // wid 0..3
  const int ar = lane & 15, g = lane >> 4;
  int blk = blockIdx.x;
  int xcd = blk & 7, j = blk >> 3;            // j 0..127
  int bh = xcd * 4 + (j & 3);
  int qh = 31 - (j >> 2);                     // big blocks dispatch first
  int b = bh >> 4, h = bh & 15;
  const ushort* Qb = Q + (size_t)bh * (2048 * 128);
  const ushort* Kb = K + (size_t)bh * (2048 * 128);
  const ushort* Vtb = Vt + (size_t)bh * (128 * 2048);
  int qrow0 = qh * 64 + wid * 16;

  auto stage = [&](int buf, int tt) {
    int kv0 = tt * 64;
#pragma unroll
    for (int i = 0; i < 4; ++i) {
      int e = (i * 256 + tid) * 16;  // byte offset, covers 16KB
      {
        int r = e >> 8, bs = (e & 255) ^ ((r & 7) << 4);
        __builtin_amdgcn_global_load_lds(
            (glb_u32_t*)(Kb + (size_t)(kv0 + r) * 128 + (bs >> 1)),
            (lds_u32_t*)((char*)kT[buf] + e), 16, 0, 0);
      }
      {
        int r = e >> 7, bs = (e & 127) ^ ((r & 7) << 4);
        __builtin_amdgcn_global_load_lds(
            (glb_u32_t*)(Vtb + (size_t)r * 2048 + kv0 + (bs >> 1)),
            (lds_u32_t*)((char*)vT[buf] + e), 16, 0, 0);
      }
    }
  };

  bf16x8 qf[4];
#pragma unroll
  for (int kk = 0; kk < 4; ++kk)
    qf[kk] = *(const bf16x8*)&Qb[(size_t)(qrow0 + ar) * 128 + kk * 32 + g * 8];
  bf16x8 vone;
#pragma unroll
  for (int jv = 0; jv < 8; ++jv) vone[jv] = (short)0x3F80;  // bf16 1.0
  float m_r[4] = {-1e30f, -1e30f, -1e30f, -1e30f};
  f32x4 lacc = (f32x4){0.f, 0.f, 0.f, 0.f};
  f32x4 accO[8];
#pragma unroll
  for (int n = 0; n < 8; ++n) accO[n] = (f32x4){0.f, 0.f, 0.f, 0.f};

  int nt = qh + 1;
  stage(0, 0);
  __syncthreads();  // publish tile 0
  for (int tt = 0; tt < nt; ++tt) {
    int cb = tt & 1;
    if (tt + 1 < nt) stage(cb ^ 1, tt + 1);  // issue early; covered by compute
    int kv0 = tt * 64;
    const ushort* kTb = kT[cb];
    const ushort* vTb = vT[cb];
    // ---- QK^T ----
    f32x4 s4[4];
    __builtin_amdgcn_s_setprio(1);
#pragma unroll
    for (int n = 0; n < 4; ++n) {
      s4[n] = (f32x4){0.f, 0.f, 0.f, 0.f};
      int r = n * 16 + ar;
      int swz = (r & 7) << 4;
#pragma unroll
      for (int kk = 0; kk < 4; ++kk) {
        int byte = (kk * 64 + g * 16) ^ swz;
        bf16x8 kf = *(const bf16x8*)&kTb[((r << 8) + byte) >> 1];
        s4[n] = __builtin_amdgcn_mfma_f32_16x16x32_bf16(qf[kk], kf, s4[n], 0, 0, 0);
      }
    }
    __builtin_amdgcn_s_setprio(0);
    // ---- softmax (log2 domain): max-reduce, defer-max rescale, exp2, pack ----
    const bool masked = (tt == nt - 1);  // only the diagonal tile needs masking
    float pv[4][4];
    float pmax[4];
#pragma unroll
    for (int r = 0; r < 4; ++r) {
      float v0 = s4[0][r], v1 = s4[1][r], v2 = s4[2][r], v3 = s4[3][r];
      if (masked) {
        int row = qrow0 + g * 4 + r;
        v0 = (kv0 + ar > row) ? -1e30f : v0;
        v1 = (kv0 + 16 + ar > row) ? -1e30f : v1;
        v2 = (kv0 + 32 + ar > row) ? -1e30f : v2;
        v3 = (kv0 + 48 + ar > row) ? -1e30f : v3;
      }
      float mx = fmaxf(fmaxf(v0, v1), fmaxf(v2, v3));
#pragma unroll
      for (int off = 1; off < 16; off <<= 1) mx = fmaxf(mx, __shfl_xor(mx, off));
      pmax[r] = mx;
      pv[r][0] = v0; pv[r][1] = v1; pv[r][2] = v2; pv[r][3] = v3;
    }
    int nore = (pmax[0] - m_r[0] <= 8.f) && (pmax[1] - m_r[1] <= 8.f) &&
               (pmax[2] - m_r[2] <= 8.f) && (pmax[3] - m_r[3] <= 8.f);
    if (!__all(nore)) {  // wave-uniform rescale (first tile always lands here)
#pragma unroll
      for (int r = 0; r < 4; ++r) {
        float mn = fmaxf(m_r[r], pmax[r]);
        float c = exp2f_fast(m_r[r] - mn);
        m_r[r] = mn;
        lacc[r] *= c;
#pragma unroll
        for (int n = 0; n < 8; ++n) accO[n][r] *= c;
      }
    }
#pragma unroll
    for (int r = 0; r < 4; ++r) {
      int qr = g * 4 + r;
      int key = ((qr & 7) << 4) ^ ((qr & 8) << 2);
      char* prow = (char*)&plds[wid][0][0] + qr * 128;
#pragma unroll
      for (int n = 0; n < 4; ++n) {
        float p = exp2f_fast(pv[r][n] - m_r[r]);
        *(ushort*)(prow + ((32 * n + 2 * ar) ^ key)) = cvt1(p);
      }
    }
    asm volatile("s_waitcnt lgkmcnt(0)" ::: "memory");
    // ---- PV + row-sum-by-ones ----
    int keyr = ((ar & 7) << 4) ^ ((ar & 8) << 2);
    const char* pbase = (const char*)&plds[wid][0][0] + ar * 128;
    bf16x8 pf0 = *(const bf16x8*)(pbase + ((g * 16) ^ keyr));
    bf16x8 pf1 = *(const bf16x8*)(pbase + ((64 + g * 16) ^ keyr));
    __builtin_amdgcn_s_setprio(1);
#pragma unroll
    for (int n = 0; n < 8; ++n) {
      int r = n * 16 + ar;
      int swz = (r & 7) << 4;
      bf16x8 vf0 = *(const bf16x8*)&vTb[((r << 7) + ((g * 16) ^ swz)) >> 1];
      accO[n] = __builtin_amdgcn_mfma_f32_16x16x32_bf16(pf0, vf0, accO[n], 0, 0, 0);
      bf16x8 vf1 = *(const bf16x8*)&vTb[((r << 7) + ((64 + g * 16) ^ swz)) >> 1];
      accO[n] = __builtin_amdgcn_mfma_f32_16x16x32_bf16(pf1, vf1, accO[n], 0, 0, 0);
    }
    lacc = __builtin_amdgcn_mfma_f32_16x16x32_bf16(pf0, vone, lacc, 0, 0, 0);
    lacc = __builtin_amdgcn_mfma_f32_16x16x32_bf16(pf1, vone, lacc, 0, 0, 0);
    __builtin_amdgcn_s_setprio(0);
    // full drain (vmcnt+lgkm) + barrier: publishes next tile, protects buffers
    __syncthreads();
  }
  // write O to [B,T,H*D] (bf16) for the O-proj GEMM
#pragma unroll
  for (int r = 0; r < 4; ++r) {
    int trow = qrow0 + g * 4 + r;
    float invl = 1.0f / lacc[r];
    ushort* orow = O + ((size_t)b * 2048 + trow) * 2048 + h * 128;
#pragma unroll
    for (int n = 0; n < 8; ++n) orow[n * 16 + ar] = cvt1(accO[n][r] * invl);
  }
}

extern "C" void kernel_launch(void* const* d_in, const int* in_sizes, int n_in,
                              void* d_out, int out_size, void* d_ws, size_t ws_size,
                              hipStream_t stream) {
  const float* x = (const float*)d_in[0];
  const float* rmsw = (const float*)d_in[1];
  const float* qkv_w = (const float*)d_in[2];
  const float* qkv_b = (const float*)d_in[3];
  const float* o_w = (const float*)d_in[4];
  const float* o_b = (const float*)d_in[5];
  float* out = (float*)d_out;

  char* ws = (char*)d_ws;
  size_t off = 0;
  auto alloc = [&](size_t bytes) {
    void* p = ws + off;
    off += (bytes + 255) & ~(size_t)255;
    return p;
  };
  ushort* xn = (ushort*)alloc((size_t)4096 * 2048 * 2);  // later reused as attn_out
  ushort* wq = (ushort*)alloc((size_t)6144 * 2048 * 2);
  ushort* wo = (ushort*)alloc((size_t)2048 * 2048 * 2);
  ushort* qb = (ushort*)alloc((size_t)32 * 2048 * 128 * 2);
  ushort* kb = (ushort*)alloc((size_t)32 * 2048 * 128 * 2);
  ushort* vb = (ushort*)alloc((size_t)32 * 2048 * 128 * 2);  // [B,H,D,T]
  float* cs = (float*)alloc((size_t)2048 * 64 * 4);
  float* sn = (float*)alloc((size_t)2048 * 64 * 4);

  // merged prologue: rmsnorm (4096 blocks) + rope table (512) + weight casts (1280)
  prologue_kernel<<<5888, 256, 0, stream>>>(x, rmsw, xn, qkv_w, wq, o_w, wo, cs, sn);
  // merged QKV: blocks [0,256) = q+k 256x256 (1 round); [256,512) = v 128x256
  gemm_qkv_kernel<<<512, 512, 0, stream>>>(xn, wq, qkv_b, qb, kb, vb, cs, sn);
  attn_kernel<<<1024, 256, 0, stream>>>(qb, kb, vb, xn /* attn_out */);
  // O-proj: M=4096 (32) x N=2048 (8) -> 256 blocks = 1 exact wave
  gemm3p_kernel<<<256, 512, 0, stream>>>(xn, wo, o_b, out);
}